// Round 3
// baseline (282.215 us; speedup 1.0000x reference)
//
#include <hip/hip_runtime.h>
#include <hip/hip_bf16.h>

// Pipeline (all fp32):
//  k_zero : zero sums/z/pooled (explicit kernel; hipMemsetAsync lowered to a
//           pathological fillBuffer dispatch in the replayed graph in R2).
//  k_stats: 8 lanes per point (lane owns one float4). s = x.w + b, rm = rowmean
//           via 3-level shfl over the 8-lane subgroup. Stores t = (s*rm, rm)
//           [exp's argument is linear in this pair: (c1*s+c2)*rm = c1*t1+c2*t2].
//           Accumulates global sum(s), sum(s^2) in f64.
//  k_pool : e = exp(c1*t1 + c2*t2); pooled[seg] += x*e, z[seg] += e.
//           Segment-uniform fast path (seg[p0]==seg[p1-1], ~99.6% of waves):
//           no seg loads, no shuffles, no branches, unrolled. Slow path for
//           boundary waves. Softmax max-shift omitted (shift-invariant; scores
//           small — validated R1/R2 absmax 6e-5).
//  k_final: pooled/(z*len), L2-normalize.

__global__ void k_zero(double* __restrict__ sums, float* __restrict__ z,
                       float* __restrict__ pooled, int B) {
  int tid = threadIdx.x;
  if (tid < 2) sums[tid] = 0.0;
  if (tid < B) z[tid] = 0.f;
  for (int i = tid; i < B * 32; i += blockDim.x) pooled[i] = 0.f;
}

__global__ __launch_bounds__(256) void k_stats(
    const float* __restrict__ x, const float* __restrict__ w,
    const float* __restrict__ bptr, float2* __restrict__ t,
    double* __restrict__ sums, int N, int chunk) {
  const int lane = threadIdx.x & 63;
  const int sub  = lane >> 3;      // which of 8 points in the batch
  const int cg   = lane & 7;       // which float4 of the point
  const float4 w4 = reinterpret_cast<const float4*>(w)[cg];
  const float bv = bptr[0];
  long gid = (long)blockIdx.x * (blockDim.x >> 6) + (threadIdx.x >> 6);
  long p0 = gid * chunk;
  long p1 = p0 + chunk; if (p1 > (long)N) p1 = N;
  double accS = 0.0, accS2 = 0.0;
  if (p0 < p1) {
    const float4* x4 = reinterpret_cast<const float4*>(x);
#pragma unroll 2
    for (long pb = p0; pb < p1; pb += 8) {
      long p = pb + sub;
      bool valid = (p < p1);
      long pc = valid ? p : (p1 - 1);
      float4 xv = x4[pc * 8 + cg];
      float d = fmaf(xv.x, w4.x, fmaf(xv.y, w4.y, fmaf(xv.z, w4.z, xv.w * w4.w)));
      float r = (xv.x + xv.y) + (xv.z + xv.w);
      d += __shfl_xor(d, 1);  r += __shfl_xor(r, 1);
      d += __shfl_xor(d, 2);  r += __shfl_xor(r, 2);
      d += __shfl_xor(d, 4);  r += __shfl_xor(r, 4);
      float s = d + bv;
      float rm = r * 0.03125f;
      if (cg == 0 && valid) {
        t[p] = make_float2(s * rm, rm);
        accS += (double)s;
        accS2 += (double)s * (double)s;
      }
    }
  }
#pragma unroll
  for (int off = 32; off > 0; off >>= 1) {
    accS  += __shfl_down(accS, off, 64);
    accS2 += __shfl_down(accS2, off, 64);
  }
  __shared__ double lds[8];
  int wid = threadIdx.x >> 6;
  if ((threadIdx.x & 63) == 0) { lds[wid*2] = accS; lds[wid*2+1] = accS2; }
  __syncthreads();
  if (threadIdx.x == 0) {
    double a = 0.0, c = 0.0;
    int nw = (int)(blockDim.x >> 6);
    for (int i = 0; i < nw; ++i) { a += lds[i*2]; c += lds[i*2+1]; }
    atomicAdd(&sums[0], a);
    atomicAdd(&sums[1], c);
  }
}

__global__ __launch_bounds__(256) void k_pool(
    const float* __restrict__ x, const float2* __restrict__ t,
    const int* __restrict__ seg, const double* __restrict__ sums,
    const float* __restrict__ gptr, const float* __restrict__ betap,
    float* __restrict__ z, float* __restrict__ pooled,
    int N, int chunk) {
  double mu  = sums[0] / (double)N;
  double var = sums[1] / (double)N - mu * mu;
  float inv = (float)(1.0 / sqrt(var + 1e-5));
  float c1 = gptr[0] * inv;                     // exponent = c1*t1 + c2*t2
  float c2 = betap[0] - c1 * (float)mu;

  const int lane = threadIdx.x & 63;
  const int sub  = lane >> 3;
  const int cg   = lane & 7;

  long gid = (long)blockIdx.x * (blockDim.x >> 6) + (threadIdx.x >> 6);
  long p0 = gid * chunk;
  long p1 = p0 + chunk; if (p1 > (long)N) p1 = N;
  if (p0 >= p1) return;

  const float4* x4 = reinterpret_cast<const float4*>(x);
  float4 acc = make_float4(0.f, 0.f, 0.f, 0.f);
  float accZ = 0.f;               // e is subgroup-uniform; only cg==0 flushed
  int segA = seg[p0];
  int segB = seg[p1 - 1];

  if (segA == segB) {
    // ---- fast path: whole chunk in one segment ----
    long pb = p0;
#pragma unroll 4
    for (; pb + 8 <= p1; pb += 8) {
      long p = pb + sub;
      float2 tv = t[p];
      float4 xv = x4[p * 8 + cg];
      float e = __expf(fmaf(c1, tv.x, c2 * tv.y));
      acc.x = fmaf(xv.x, e, acc.x);
      acc.y = fmaf(xv.y, e, acc.y);
      acc.z = fmaf(xv.z, e, acc.z);
      acc.w = fmaf(xv.w, e, acc.w);
      accZ += e;
    }
    if (pb < p1) {                // partial tail batch
      long p = pb + sub;
      bool valid = (p < p1);
      long pc = valid ? p : (p1 - 1);
      float2 tv = t[pc];
      float4 xv = x4[pc * 8 + cg];
      float e = valid ? __expf(fmaf(c1, tv.x, c2 * tv.y)) : 0.f;
      acc.x = fmaf(xv.x, e, acc.x);
      acc.y = fmaf(xv.y, e, acc.y);
      acc.z = fmaf(xv.z, e, acc.z);
      acc.w = fmaf(xv.w, e, acc.w);
      accZ += e;
    }
    // wave-reduce across the 8 subgroups, single flush
#pragma unroll
    for (int off = 8; off < 64; off <<= 1) {
      acc.x += __shfl_xor(acc.x, off);
      acc.y += __shfl_xor(acc.y, off);
      acc.z += __shfl_xor(acc.z, off);
      acc.w += __shfl_xor(acc.w, off);
      accZ  += __shfl_xor(accZ, off);
    }
    if (sub == 0) {
      atomicAdd(&pooled[segA * 32 + cg * 4 + 0], acc.x);
      atomicAdd(&pooled[segA * 32 + cg * 4 + 1], acc.y);
      atomicAdd(&pooled[segA * 32 + cg * 4 + 2], acc.z);
      atomicAdd(&pooled[segA * 32 + cg * 4 + 3], acc.w);
      if (cg == 0) atomicAdd(&z[segA], accZ);
    }
  } else {
    // ---- slow path: chunk crosses a segment boundary (<= ~62 waves) ----
    int curSeg = segA;
    for (long pb = p0; pb < p1; pb += 8) {
      long p = pb + sub;
      bool valid = (p < p1);
      long pc = valid ? p : (p1 - 1);
      int sg = seg[pc];
      float2 tv = t[pc];
      float4 xv = x4[pc * 8 + cg];
      float e = valid ? __expf(fmaf(c1, tv.x, c2 * tv.y)) : 0.f;
      if (sg != curSeg) {
        atomicAdd(&pooled[curSeg * 32 + cg * 4 + 0], acc.x);
        atomicAdd(&pooled[curSeg * 32 + cg * 4 + 1], acc.y);
        atomicAdd(&pooled[curSeg * 32 + cg * 4 + 2], acc.z);
        atomicAdd(&pooled[curSeg * 32 + cg * 4 + 3], acc.w);
        if (cg == 0) atomicAdd(&z[curSeg], accZ);
        acc = make_float4(0.f, 0.f, 0.f, 0.f);
        accZ = 0.f;
        curSeg = sg;
      }
      acc.x = fmaf(xv.x, e, acc.x);
      acc.y = fmaf(xv.y, e, acc.y);
      acc.z = fmaf(xv.z, e, acc.z);
      acc.w = fmaf(xv.w, e, acc.w);
      accZ += e;
    }
    atomicAdd(&pooled[curSeg * 32 + cg * 4 + 0], acc.x);
    atomicAdd(&pooled[curSeg * 32 + cg * 4 + 1], acc.y);
    atomicAdd(&pooled[curSeg * 32 + cg * 4 + 2], acc.z);
    atomicAdd(&pooled[curSeg * 32 + cg * 4 + 3], acc.w);
    if (cg == 0) atomicAdd(&z[curSeg], accZ);
  }
}

__global__ void k_final(const float* __restrict__ pooled, const float* __restrict__ z,
                        const int* __restrict__ length, float* __restrict__ out, int B) {
  int tid = threadIdx.x;
  if (tid >= B * 32) return;
  int b = tid >> 5;
  float v = pooled[tid] / (z[b] * (float)length[b]);
  float sq = v * v;
#pragma unroll
  for (int off = 16; off > 0; off >>= 1) sq += __shfl_xor(sq, off, 32);
  float norm = sqrtf(sq);
  out[tid] = v / fmaxf(norm, 1e-12f);
}

extern "C" void kernel_launch(void* const* d_in, const int* in_sizes, int n_in,
                              void* d_out, int out_size, void* d_ws, size_t ws_size,
                              hipStream_t stream) {
  const float* x     = (const float*)d_in[0];
  const float* w     = (const float*)d_in[1];
  const float* b     = (const float*)d_in[2];
  const float* gamma = (const float*)d_in[3];
  const float* beta  = (const float*)d_in[4];
  const int* length  = (const int*)d_in[5];
  const int* seg     = (const int*)d_in[6];
  int N = in_sizes[6];          // 3,170,000
  int B = in_sizes[5];          // 32
  float* out = (float*)d_out;

  char* ws = (char*)d_ws;
  double* sums   = (double*)ws;                      // 2 doubles
  float*  z      = (float*)(ws + 16);                // B floats
  float*  pooled = (float*)(ws + 16 + (size_t)B*4);  // B*32 floats
  size_t statsBytes = 16 + (size_t)B*4 + (size_t)B*32*4;
  size_t tOff = (statsBytes + 15) & ~(size_t)15;
  float2* t = (float2*)(ws + tOff);                  // N float2

  const int threads = 256;
  const int blocks = 2048;                             // 8 blocks/CU
  const int nWaves = blocks * (threads / 64);          // 8192
  const int chunk = (N + nWaves - 1) / nWaves;         // ~387 points per wave

  k_zero<<<1, 256, 0, stream>>>(sums, z, pooled, B);
  k_stats<<<blocks, threads, 0, stream>>>(x, w, b, t, sums, N, chunk);
  k_pool<<<blocks, threads, 0, stream>>>(x, t, seg, sums, gamma, beta, z, pooled, N, chunk);
  k_final<<<1, B * 32, 0, stream>>>(pooled, z, length, out, B);
}

// Round 4
// 252.318 us; speedup vs baseline: 1.1185x; 1.1185x over previous
//
#include <hip/hip_runtime.h>
#include <hip/hip_bf16.h>

// Pipeline (all fp32):
//  k_zero : zero sums/z/pooled (tiny explicit kernel; async-memset was pathological in-graph).
//  k_stats: thread-per-point (R1-proven 5.1 TB/s pattern): 8 independent float4 loads,
//           s = x.w + b, rm = rowmean; stores t = (s*rm, rm)  [exp arg = c1*t1 + c2*t2];
//           f64 sum(s), sum(s^2) via wave+block reduce -> 2 atomics/block.
//  k_pool : 8 lanes per point (lane owns a float4); wave = 8 points/iter = 1KB x + 64B t.
//           e = exp(c1*t1+c2*t2)  (max-shift omitted: softmax is shift-invariant, scores
//           small — validated absmax 6e-5 in R1-R3). Register-accumulate pooled + z;
//           segment-uniform fast path (seg[p0]==seg[p1-1], ~99.6% of waves) has no seg
//           loads, no branches, unroll 8; slow path for the ~31 boundary waves.
//  k_final: pooled/(z*len), L2-normalize.

__global__ void k_zero(double* __restrict__ sums, float* __restrict__ z,
                       float* __restrict__ pooled, int B) {
  int tid = threadIdx.x;
  if (tid < 2) sums[tid] = 0.0;
  if (tid < B) z[tid] = 0.f;
  for (int i = tid; i < B * 32; i += blockDim.x) pooled[i] = 0.f;
}

__global__ __launch_bounds__(256) void k_stats(
    const float* __restrict__ x, const float* __restrict__ w,
    const float* __restrict__ bptr, float2* __restrict__ t,
    double* __restrict__ sums, int N) {
  int tid = blockIdx.x * blockDim.x + threadIdx.x;
  int stride = gridDim.x * blockDim.x;
  float wreg[32];
#pragma unroll
  for (int j = 0; j < 32; ++j) wreg[j] = w[j];
  const float bv = bptr[0];
  double accS = 0.0, accS2 = 0.0;
  for (int p = tid; p < N; p += stride) {
    const float4* xp = reinterpret_cast<const float4*>(x) + (size_t)p * 8;
    float dot = 0.f, rsum = 0.f;
#pragma unroll
    for (int q = 0; q < 8; ++q) {
      float4 v = xp[q];
      dot  += v.x * wreg[4*q] + v.y * wreg[4*q+1] + v.z * wreg[4*q+2] + v.w * wreg[4*q+3];
      rsum += (v.x + v.y) + (v.z + v.w);
    }
    float s = dot + bv;
    float rm = rsum * 0.03125f;
    t[p] = make_float2(s * rm, rm);
    accS += (double)s;
    accS2 += (double)s * (double)s;
  }
#pragma unroll
  for (int off = 32; off > 0; off >>= 1) {
    accS  += __shfl_down(accS, off, 64);
    accS2 += __shfl_down(accS2, off, 64);
  }
  __shared__ double lds[8];
  int wid = threadIdx.x >> 6;
  if ((threadIdx.x & 63) == 0) { lds[wid*2] = accS; lds[wid*2+1] = accS2; }
  __syncthreads();
  if (threadIdx.x == 0) {
    double a = 0.0, c = 0.0;
    int nw = (int)(blockDim.x >> 6);
    for (int i = 0; i < nw; ++i) { a += lds[i*2]; c += lds[i*2+1]; }
    atomicAdd(&sums[0], a);
    atomicAdd(&sums[1], c);
  }
}

__global__ __launch_bounds__(256) void k_pool(
    const float* __restrict__ x, const float2* __restrict__ t,
    const int* __restrict__ seg, const double* __restrict__ sums,
    const float* __restrict__ gptr, const float* __restrict__ betap,
    float* __restrict__ z, float* __restrict__ pooled,
    int N, int chunk) {
  double mu  = sums[0] / (double)N;
  double var = sums[1] / (double)N - mu * mu;
  float inv = (float)(1.0 / sqrt(var + 1e-5));
  const float c1 = gptr[0] * inv;                 // exponent = c1*t1 + c2*t2
  const float c2 = betap[0] - c1 * (float)mu;

  const int lane = threadIdx.x & 63;
  const int sub  = lane >> 3;      // point slot within the wave's 8-point batch
  const int cg   = lane & 7;       // which float4 of the point

  int gid = blockIdx.x * (blockDim.x >> 6) + (threadIdx.x >> 6);
  int p0 = gid * chunk;                     // chunk is a multiple of 8
  if (p0 >= N) return;
  int p1 = p0 + chunk; if (p1 > N) p1 = N;

  const float4* x4 = reinterpret_cast<const float4*>(x);
  float4 acc = make_float4(0.f, 0.f, 0.f, 0.f);
  float accZ = 0.f;                // e is subgroup-uniform; only cg==0 flushed
  const int segA = seg[p0];
  const int segB = seg[p1 - 1];

  if (segA == segB) {
    // ---- fast path: whole chunk in one segment ----
    int nfull = (p1 - p0) & ~7;    // all batches full except possibly last wave's tail
    int pb = p0;
#pragma unroll 8
    for (; pb < p0 + nfull; pb += 8) {
      int p = pb + sub;
      float2 tv = t[p];
      float4 xv = x4[p * 8 + cg];
      float e = __expf(fmaf(c1, tv.x, c2 * tv.y));
      acc.x = fmaf(xv.x, e, acc.x);
      acc.y = fmaf(xv.y, e, acc.y);
      acc.z = fmaf(xv.z, e, acc.z);
      acc.w = fmaf(xv.w, e, acc.w);
      accZ += e;
    }
    if (pb < p1) {                 // partial tail batch (last active wave only)
      int p = pb + sub;
      bool valid = (p < p1);
      int pc = valid ? p : (p1 - 1);
      float2 tv = t[pc];
      float4 xv = x4[pc * 8 + cg];
      float e = valid ? __expf(fmaf(c1, tv.x, c2 * tv.y)) : 0.f;
      acc.x = fmaf(xv.x, e, acc.x);
      acc.y = fmaf(xv.y, e, acc.y);
      acc.z = fmaf(xv.z, e, acc.z);
      acc.w = fmaf(xv.w, e, acc.w);
      accZ += e;
    }
#pragma unroll
    for (int off = 8; off < 64; off <<= 1) {   // reduce across the 8 point slots
      acc.x += __shfl_xor(acc.x, off);
      acc.y += __shfl_xor(acc.y, off);
      acc.z += __shfl_xor(acc.z, off);
      acc.w += __shfl_xor(acc.w, off);
      accZ  += __shfl_xor(accZ, off);
    }
    if (sub == 0) {
      atomicAdd(&pooled[segA * 32 + cg * 4 + 0], acc.x);
      atomicAdd(&pooled[segA * 32 + cg * 4 + 1], acc.y);
      atomicAdd(&pooled[segA * 32 + cg * 4 + 2], acc.z);
      atomicAdd(&pooled[segA * 32 + cg * 4 + 3], acc.w);
      if (cg == 0) atomicAdd(&z[segA], accZ);
    }
  } else {
    // ---- slow path: chunk crosses a segment boundary (~31 waves total) ----
    int curSeg = segA;
    for (int pb = p0; pb < p1; pb += 8) {
      int p = pb + sub;
      bool valid = (p < p1);
      int pc = valid ? p : (p1 - 1);
      int sg = seg[pc];
      float2 tv = t[pc];
      float4 xv = x4[pc * 8 + cg];
      float e = valid ? __expf(fmaf(c1, tv.x, c2 * tv.y)) : 0.f;
      if (sg != curSeg) {
        atomicAdd(&pooled[curSeg * 32 + cg * 4 + 0], acc.x);
        atomicAdd(&pooled[curSeg * 32 + cg * 4 + 1], acc.y);
        atomicAdd(&pooled[curSeg * 32 + cg * 4 + 2], acc.z);
        atomicAdd(&pooled[curSeg * 32 + cg * 4 + 3], acc.w);
        if (cg == 0) atomicAdd(&z[curSeg], accZ);
        acc = make_float4(0.f, 0.f, 0.f, 0.f);
        accZ = 0.f;
        curSeg = sg;
      }
      acc.x = fmaf(xv.x, e, acc.x);
      acc.y = fmaf(xv.y, e, acc.y);
      acc.z = fmaf(xv.z, e, acc.z);
      acc.w = fmaf(xv.w, e, acc.w);
      accZ += e;
    }
    atomicAdd(&pooled[curSeg * 32 + cg * 4 + 0], acc.x);
    atomicAdd(&pooled[curSeg * 32 + cg * 4 + 1], acc.y);
    atomicAdd(&pooled[curSeg * 32 + cg * 4 + 2], acc.z);
    atomicAdd(&pooled[curSeg * 32 + cg * 4 + 3], acc.w);
    if (cg == 0) atomicAdd(&z[curSeg], accZ);
  }
}

__global__ void k_final(const float* __restrict__ pooled, const float* __restrict__ z,
                        const int* __restrict__ length, float* __restrict__ out, int B) {
  int tid = threadIdx.x;
  if (tid >= B * 32) return;
  int b = tid >> 5;
  float v = pooled[tid] / (z[b] * (float)length[b]);
  float sq = v * v;
#pragma unroll
  for (int off = 16; off > 0; off >>= 1) sq += __shfl_xor(sq, off, 32);
  float norm = sqrtf(sq);
  out[tid] = v / fmaxf(norm, 1e-12f);
}

extern "C" void kernel_launch(void* const* d_in, const int* in_sizes, int n_in,
                              void* d_out, int out_size, void* d_ws, size_t ws_size,
                              hipStream_t stream) {
  const float* x     = (const float*)d_in[0];
  const float* w     = (const float*)d_in[1];
  const float* b     = (const float*)d_in[2];
  const float* gamma = (const float*)d_in[3];
  const float* beta  = (const float*)d_in[4];
  const int* length  = (const int*)d_in[5];
  const int* seg     = (const int*)d_in[6];
  int N = in_sizes[6];          // 3,170,000
  int B = in_sizes[5];          // 32
  float* out = (float*)d_out;

  char* ws = (char*)d_ws;
  double* sums   = (double*)ws;                      // 2 doubles
  float*  z      = (float*)(ws + 16);                // B floats
  float*  pooled = (float*)(ws + 16 + (size_t)B*4);  // B*32 floats
  size_t statsBytes = 16 + (size_t)B*4 + (size_t)B*32*4;
  size_t tOff = (statsBytes + 15) & ~(size_t)15;
  float2* t = (float2*)(ws + tOff);                  // N float2

  const int threads = 256;
  const int blocks = 2048;                             // 8 blocks/CU
  const int nWaves = blocks * (threads / 64);          // 8192
  int chunk = (N + nWaves - 1) / nWaves;
  chunk = (chunk + 7) & ~7;                            // multiple of 8 -> no inner tails

  k_zero<<<1, 256, 0, stream>>>(sums, z, pooled, B);
  k_stats<<<blocks, threads, 0, stream>>>(x, w, b, t, sums, N);
  k_pool<<<blocks, threads, 0, stream>>>(x, t, seg, sums, gamma, beta, z, pooled, N, chunk);
  k_final<<<1, B * 32, 0, stream>>>(pooled, z, length, out, B);
}